// Round 3
// baseline (201.856 us; speedup 1.0000x reference)
//
#include <hip/hip_runtime.h>

#define N_NODES_C 8192
#define MAX_PATH_C 5
#define EDGE_DIM_C 32

typedef unsigned int uint4_v __attribute__((ext_vector_type(4)));

// Fast zero-fill: grid-stride 16B nontemporal stores.
__global__ void __launch_bounds__(256) ee_zero(uint4_v* __restrict__ out, long long n16)
{
    long long i = (long long)blockIdx.x * blockDim.x + threadIdx.x;
    long long stride = (long long)gridDim.x * blockDim.x;
    uint4_v z = (uint4_v)(0u);
    for (; i < n16; i += stride)
        __builtin_nontemporal_store(z, &out[i]);
}

// Pass 1: tag each output cell with (max path index + 1) -> numpy last-write-wins.
__global__ void __launch_bounds__(256) ee_pass1_winner(
    const int* __restrict__ src, const int* __restrict__ dst,
    unsigned int* __restrict__ outw, int P)
{
    int p = blockIdx.x * blockDim.x + threadIdx.x;
    if (p >= P) return;
    long long cell = (long long)src[p] * N_NODES_C + (long long)dst[p];
    atomicMax(outw + cell, (unsigned int)(p + 1));
}

// Pass 2: winner path replaces its tag with the encoded value.
__global__ void __launch_bounds__(256) ee_pass2_enc(
    const float* __restrict__ edge_attr,
    const float* __restrict__ edge_weights,
    const int* __restrict__ paths,
    const int* __restrict__ path_lens,
    const int* __restrict__ src, const int* __restrict__ dst,
    float* __restrict__ out, int P)
{
    __shared__ __align__(16) float w[MAX_PATH_C * EDGE_DIM_C];
    for (int i = threadIdx.x; i < MAX_PATH_C * EDGE_DIM_C; i += blockDim.x)
        w[i] = edge_weights[i];
    __syncthreads();

    int p = blockIdx.x * blockDim.x + threadIdx.x;
    if (p >= P) return;

    long long cell = (long long)src[p] * N_NODES_C + (long long)dst[p];
    const unsigned int* outw = (const unsigned int*)out;
    if (outw[cell] != (unsigned int)(p + 1)) return;  // not the last writer

    int len = (int)path_lens[p];
    float s = 0.0f;
    #pragma unroll
    for (int l = 0; l < MAX_PATH_C; ++l) {
        if (l < len) {
            long long e = (long long)paths[p * MAX_PATH_C + l];
            const float4* __restrict__ row =
                (const float4*)(edge_attr + e * EDGE_DIM_C);
            const float4* wr = (const float4*)(w + l * EDGE_DIM_C);
            float acc = 0.0f;
            #pragma unroll
            for (int j = 0; j < EDGE_DIM_C / 4; ++j) {
                float4 a = row[j];
                float4 b = wr[j];
                acc += a.x * b.x + a.y * b.y + a.z * b.z + a.w * b.w;
            }
            s += acc;
        }
    }
    float enc = (len > 0) ? s / (float)len : 0.0f;
    if (isnan(enc)) enc = 0.0f;  // nan_to_num
    out[cell] = enc;
}

extern "C" void kernel_launch(void* const* d_in, const int* in_sizes, int n_in,
                              void* d_out, int out_size, void* d_ws, size_t ws_size,
                              hipStream_t stream)
{
    // inputs: 0:x(f32) 1:edge_attr(f32) 2:edge_weights(f32)
    //         3:paths(int) 4:path_lens(int) 5:src(int) 6:dst(int)
    const float* edge_attr    = (const float*)d_in[1];
    const float* edge_weights = (const float*)d_in[2];
    const int*   paths        = (const int*)d_in[3];
    const int*   path_lens    = (const int*)d_in[4];
    const int*   src          = (const int*)d_in[5];
    const int*   dst          = (const int*)d_in[6];
    float* out = (float*)d_out;
    const int P = in_sizes[4];

    // 8192*8192 floats = 16Mi 16B-vectors; zero with wide streaming stores.
    long long n16 = (long long)out_size / 4;
    ee_zero<<<2048, 256, 0, stream>>>((uint4_v*)out, n16);

    const int threads = 256;
    const int blocks = (P + threads - 1) / threads;
    ee_pass1_winner<<<blocks, threads, 0, stream>>>(
        src, dst, (unsigned int*)out, P);
    ee_pass2_enc<<<blocks, threads, 0, stream>>>(
        edge_attr, edge_weights, paths, path_lens, src, dst, out, P);
}

// Round 4
// 175.758 us; speedup vs baseline: 1.1485x; 1.1485x over previous
//
#include <hip/hip_runtime.h>

#define N_NODES_C 8192
#define MAX_PATH_C 5
#define EDGE_DIM_C 32

typedef unsigned int uint4_v __attribute__((ext_vector_type(4)));

// Fast zero-fill: grid-stride 16B cache-allocating stores (NOT nontemporal —
// the tag region must stay MALL/L2-resident for pass1 atomics + pass2 reads).
__global__ void __launch_bounds__(256) ee_zero(uint4_v* __restrict__ out, long long n16)
{
    long long i = (long long)blockIdx.x * blockDim.x + threadIdx.x;
    long long stride = (long long)gridDim.x * blockDim.x;
    uint4_v z = (uint4_v)(0u);
    for (; i < n16; i += stride)
        out[i] = z;
}

// Pass 1: tag each output cell with (max path index + 1) -> numpy last-write-wins.
__global__ void __launch_bounds__(256) ee_pass1_winner(
    const int* __restrict__ src, const int* __restrict__ dst,
    unsigned int* __restrict__ outw, int P)
{
    int p = blockIdx.x * blockDim.x + threadIdx.x;
    if (p >= P) return;
    long long cell = (long long)src[p] * N_NODES_C + (long long)dst[p];
    atomicMax(outw + cell, (unsigned int)(p + 1));
}

// Pass 2: winner path replaces its tag with the encoded value.
__global__ void __launch_bounds__(256) ee_pass2_enc(
    const float* __restrict__ edge_attr,
    const float* __restrict__ edge_weights,
    const int* __restrict__ paths,
    const int* __restrict__ path_lens,
    const int* __restrict__ src, const int* __restrict__ dst,
    float* __restrict__ out, int P)
{
    __shared__ __align__(16) float w[MAX_PATH_C * EDGE_DIM_C];
    for (int i = threadIdx.x; i < MAX_PATH_C * EDGE_DIM_C; i += blockDim.x)
        w[i] = edge_weights[i];
    __syncthreads();

    int p = blockIdx.x * blockDim.x + threadIdx.x;
    if (p >= P) return;

    long long cell = (long long)src[p] * N_NODES_C + (long long)dst[p];
    const unsigned int* outw = (const unsigned int*)out;
    if (outw[cell] != (unsigned int)(p + 1)) return;  // not the last writer

    int len = (int)path_lens[p];
    float s = 0.0f;
    #pragma unroll
    for (int l = 0; l < MAX_PATH_C; ++l) {
        if (l < len) {
            long long e = (long long)paths[p * MAX_PATH_C + l];
            const float4* __restrict__ row =
                (const float4*)(edge_attr + e * EDGE_DIM_C);
            const float4* wr = (const float4*)(w + l * EDGE_DIM_C);
            float acc = 0.0f;
            #pragma unroll
            for (int j = 0; j < EDGE_DIM_C / 4; ++j) {
                float4 a = row[j];
                float4 b = wr[j];
                acc += a.x * b.x + a.y * b.y + a.z * b.z + a.w * b.w;
            }
            s += acc;
        }
    }
    float enc = (len > 0) ? s / (float)len : 0.0f;
    if (isnan(enc)) enc = 0.0f;  // nan_to_num
    out[cell] = enc;
}

extern "C" void kernel_launch(void* const* d_in, const int* in_sizes, int n_in,
                              void* d_out, int out_size, void* d_ws, size_t ws_size,
                              hipStream_t stream)
{
    // inputs: 0:x(f32) 1:edge_attr(f32) 2:edge_weights(f32)
    //         3:paths(int) 4:path_lens(int) 5:src(int) 6:dst(int)
    const float* edge_attr    = (const float*)d_in[1];
    const float* edge_weights = (const float*)d_in[2];
    const int*   paths        = (const int*)d_in[3];
    const int*   path_lens    = (const int*)d_in[4];
    const int*   src          = (const int*)d_in[5];
    const int*   dst          = (const int*)d_in[6];
    float* out = (float*)d_out;
    const int P = in_sizes[4];

    // 8192*8192 floats = 16Mi 16B-vectors; zero with wide plain stores.
    // 4096 blocks: enough to saturate write BW (rocclr's size-scaled grid
    // only managed 1.66 TB/s on this 256MB buffer).
    long long n16 = (long long)out_size / 4;
    ee_zero<<<4096, 256, 0, stream>>>((uint4_v*)out, n16);

    const int threads = 256;
    const int blocks = (P + threads - 1) / threads;
    ee_pass1_winner<<<blocks, threads, 0, stream>>>(
        src, dst, (unsigned int*)out, P);
    ee_pass2_enc<<<blocks, threads, 0, stream>>>(
        edge_attr, edge_weights, paths, path_lens, src, dst, out, P);
}

// Round 5
// 174.558 us; speedup vs baseline: 1.1564x; 1.0069x over previous
//
#include <hip/hip_runtime.h>

#define N_NODES_C 8192
#define MAX_PATH_C 5
#define EDGE_DIM_C 32

typedef unsigned int uint4_v __attribute__((ext_vector_type(4)));

// ---- d_ws layout (32-bit words) ----
// cnt:    [0,      8192)
// offs:   [8192,   16385)   (8193 entries)
// cursor: [24576,  32768)
// pathid: [32768,  32768+1M)
// enc:    [1081344, 1081344+1M)  (floats)
#define WS_CNT    0
#define WS_OFFS   8192
#define WS_CURSOR 24576
#define WS_PATHID 32768
#define WS_ENC    (32768 + 1048576)

__global__ void __launch_bounds__(256) k_init(unsigned int* __restrict__ cnt)
{
    int i = blockIdx.x * blockDim.x + threadIdx.x;
    if (i < N_NODES_C) cnt[i] = 0u;
}

// Histogram by src row + precompute per-path encoding value.
__global__ void __launch_bounds__(256) k_hist_enc(
    const float* __restrict__ edge_attr,
    const float* __restrict__ edge_weights,
    const int* __restrict__ paths,
    const int* __restrict__ path_lens,
    const int* __restrict__ src,
    unsigned int* __restrict__ cnt,
    float* __restrict__ enc_out, int P)
{
    __shared__ __align__(16) float w[MAX_PATH_C * EDGE_DIM_C];
    for (int i = threadIdx.x; i < MAX_PATH_C * EDGE_DIM_C; i += blockDim.x)
        w[i] = edge_weights[i];
    __syncthreads();

    int p = blockIdx.x * blockDim.x + threadIdx.x;
    if (p >= P) return;

    atomicAdd(&cnt[src[p]], 1u);

    int len = path_lens[p];
    float s = 0.0f;
    #pragma unroll
    for (int l = 0; l < MAX_PATH_C; ++l) {
        if (l < len) {
            long long e = (long long)paths[p * MAX_PATH_C + l];
            const float4* __restrict__ row =
                (const float4*)(edge_attr + e * EDGE_DIM_C);
            const float4* wr = (const float4*)(w + l * EDGE_DIM_C);
            float acc = 0.0f;
            #pragma unroll
            for (int j = 0; j < EDGE_DIM_C / 4; ++j) {
                float4 a = row[j];
                float4 b = wr[j];
                acc += a.x * b.x + a.y * b.y + a.z * b.z + a.w * b.w;
            }
            s += acc;
        }
    }
    float enc = (len > 0) ? s / (float)len : 0.0f;
    if (isnan(enc)) enc = 0.0f;  // nan_to_num
    enc_out[p] = enc;
}

// Exclusive prefix sum over 8192 counters; writes offs[0..8192] and cursor.
__global__ void __launch_bounds__(1024) k_scan(
    const unsigned int* __restrict__ cnt,
    unsigned int* __restrict__ offs,
    unsigned int* __restrict__ cursor)
{
    __shared__ unsigned int part[1024];
    int t = threadIdx.x;
    unsigned int local[8];
    unsigned int mysum = 0;
    #pragma unroll
    for (int j = 0; j < 8; ++j) { local[j] = cnt[t * 8 + j]; mysum += local[j]; }
    part[t] = mysum;
    __syncthreads();
    for (int off = 1; off < 1024; off <<= 1) {
        unsigned int v = 0;
        if (t >= off) v = part[t - off];
        __syncthreads();
        if (t >= off) part[t] += v;
        __syncthreads();
    }
    unsigned int run = part[t] - mysum;  // exclusive base
    #pragma unroll
    for (int j = 0; j < 8; ++j) {
        offs[t * 8 + j] = run;
        cursor[t * 8 + j] = run;
        run += local[j];
    }
    if (t == 1023) offs[N_NODES_C] = run;
}

// Bucket path ids by src row.
__global__ void __launch_bounds__(256) k_scatter(
    const int* __restrict__ src,
    unsigned int* __restrict__ cursor,
    unsigned int* __restrict__ pathid, int P)
{
    int p = blockIdx.x * blockDim.x + threadIdx.x;
    if (p >= P) return;
    unsigned int pos = atomicAdd(&cursor[src[p]], 1u);
    pathid[pos] = (unsigned int)p;
}

// One block per output row: build row in LDS, stream out with NT stores.
// d_out is written exactly once per line, by a fixed owner block, never read.
__global__ void __launch_bounds__(256) k_sweep(
    const unsigned int* __restrict__ offs,
    const unsigned int* __restrict__ pathid,
    const float* __restrict__ enc,
    const int* __restrict__ dst,
    float* __restrict__ out)
{
    __shared__ __align__(16) unsigned int row[N_NODES_C];
    const int r = blockIdx.x;
    const int t = threadIdx.x;

    uint4_v* row4 = (uint4_v*)row;
    uint4_v z = (uint4_v)(0u);
    #pragma unroll
    for (int j = 0; j < 8; ++j) row4[j * 256 + t] = z;
    __syncthreads();

    const unsigned int beg = offs[r], end = offs[r + 1];
    for (unsigned int i = beg + t; i < end; i += 256) {
        unsigned int p = pathid[i];
        atomicMax(&row[dst[p]], p + 1u);  // last-write-wins tag
    }
    __syncthreads();
    for (unsigned int i = beg + t; i < end; i += 256) {
        unsigned int p = pathid[i];
        int d = dst[p];
        if (row[d] == p + 1u) row[d] = __float_as_uint(enc[p]);
    }
    __syncthreads();

    uint4_v* out4 = (uint4_v*)(out + (size_t)r * N_NODES_C);
    #pragma unroll
    for (int j = 0; j < 8; ++j)
        __builtin_nontemporal_store(row4[j * 256 + t], &out4[j * 256 + t]);
}

extern "C" void kernel_launch(void* const* d_in, const int* in_sizes, int n_in,
                              void* d_out, int out_size, void* d_ws, size_t ws_size,
                              hipStream_t stream)
{
    // inputs: 0:x 1:edge_attr 2:edge_weights 3:paths 4:path_lens 5:src 6:dst
    const float* edge_attr    = (const float*)d_in[1];
    const float* edge_weights = (const float*)d_in[2];
    const int*   paths        = (const int*)d_in[3];
    const int*   path_lens    = (const int*)d_in[4];
    const int*   src          = (const int*)d_in[5];
    const int*   dst          = (const int*)d_in[6];
    float* out = (float*)d_out;
    const int P = in_sizes[4];

    unsigned int* ws_u = (unsigned int*)d_ws;
    unsigned int* cnt    = ws_u + WS_CNT;
    unsigned int* offs   = ws_u + WS_OFFS;
    unsigned int* cursor = ws_u + WS_CURSOR;
    unsigned int* pathid = ws_u + WS_PATHID;
    float*        enc    = (float*)(ws_u + WS_ENC);

    const int threads = 256;
    const int pblocks = (P + threads - 1) / threads;

    k_init<<<(N_NODES_C + threads - 1) / threads, threads, 0, stream>>>(cnt);
    k_hist_enc<<<pblocks, threads, 0, stream>>>(
        edge_attr, edge_weights, paths, path_lens, src, cnt, enc, P);
    k_scan<<<1, 1024, 0, stream>>>(cnt, offs, cursor);
    k_scatter<<<pblocks, threads, 0, stream>>>(src, cursor, pathid, P);
    k_sweep<<<N_NODES_C, threads, 0, stream>>>(offs, pathid, enc, dst, out);
}